// Round 2
// baseline (3408.562 us; speedup 1.0000x reference)
//
#include <hip/hip_runtime.h>
#include <math.h>

// Round 1 resubmit: GPU broker timed out twice; this fp32 baseline is still
// unmeasured. Identical logic to round 0.

#define B_    2
#define S_    2048
#define D_    2048
#define H_    16
#define HD_   128
#define M_    (B_ * S_)          // 4096 rows
#define NQKV_ (3 * H_ * HD_)     // 6144

#define QT 64                    // q rows per attention block
#define KT 32                    // k/v rows per tile

// ---------------------------------------------------------------------------
// fp32 GEMM: C[M,N] = A[M,K] @ B[K,N], all row-major. 128x128 tile, BK=16,
// 256 threads, 8x8 per thread. Column ownership per thread is the two float4
// chunks {tx*4..tx*4+3} and {64+tx*4..}, which makes LDS B-reads 16
// consecutive granules (2-way, free) and — for the QKV GEMM — puts the RoPE
// rotate pair (d, d+64) inside one thread's accumulator.
// ---------------------------------------------------------------------------
template <bool ROPE>
__global__ __launch_bounds__(256) void gemm_f32_kernel(
    const float* __restrict__ A, const float* __restrict__ Bw,
    float* __restrict__ C, int M, int N, int K) {
  constexpr int BM = 128, BN = 128, BK = 16;
  __shared__ float As[BK][BM + 4];   // stored transposed; +4 keeps float4 align
  __shared__ float Bs[BK][BN + 4];
  const int tid = threadIdx.x;
  const int ty = tid >> 4, tx = tid & 15;
  const int m0 = blockIdx.y * BM;
  const int n0 = blockIdx.x * BN;

  float acc[8][8];
#pragma unroll
  for (int i = 0; i < 8; ++i)
#pragma unroll
    for (int j = 0; j < 8; ++j) acc[i][j] = 0.f;

  const float* Ab = A + (size_t)m0 * K;
  const float* Bb = Bw + n0;

  for (int k0 = 0; k0 < K; k0 += BK) {
    // A tile: 128x16. Each thread: 2 float4 loads, scatter-transpose to As.
#pragma unroll
    for (int it = 0; it < (BM * BK) / (4 * 256); ++it) {
      int f = tid + it * 256;        // 0..511
      int r = f >> 2, k4 = f & 3;
      float4 v = *(const float4*)(Ab + (size_t)r * K + k0 + k4 * 4);
      As[k4 * 4 + 0][r] = v.x;
      As[k4 * 4 + 1][r] = v.y;
      As[k4 * 4 + 2][r] = v.z;
      As[k4 * 4 + 3][r] = v.w;
    }
    // B tile: 16x128, coalesced float4 row loads.
#pragma unroll
    for (int it = 0; it < (BK * BN) / (4 * 256); ++it) {
      int f = tid + it * 256;
      int r = f >> 5, c4 = f & 31;
      *(float4*)&Bs[r][c4 * 4] =
          *(const float4*)(Bb + (size_t)(k0 + r) * N + c4 * 4);
    }
    __syncthreads();
#pragma unroll
    for (int k = 0; k < BK; ++k) {
      float a[8], bb[8];
      *(float4*)&a[0] = *(const float4*)&As[k][ty * 8];
      *(float4*)&a[4] = *(const float4*)&As[k][ty * 8 + 4];
      *(float4*)&bb[0] = *(const float4*)&Bs[k][tx * 4];
      *(float4*)&bb[4] = *(const float4*)&Bs[k][64 + tx * 4];
#pragma unroll
      for (int i = 0; i < 8; ++i)
#pragma unroll
        for (int j = 0; j < 8; ++j) acc[i][j] = fmaf(a[i], bb[j], acc[i][j]);
    }
    __syncthreads();
  }

  // Fused RoPE epilogue: only for the Q and K sections (n0 < 4096). This
  // 128-col tile is exactly one head; halves pair as acc[i][jj] / acc[i][jj+4].
  if (ROPE && n0 < 2 * H_ * HD_) {
    float invf[4];
#pragma unroll
    for (int jj = 0; jj < 4; ++jj)
      invf[jj] = 1.0f / powf(10000.0f, (float)(tx * 4 + jj) * (1.0f / 64.0f));
#pragma unroll
    for (int i = 0; i < 8; ++i) {
      int srow = (m0 + ty * 8 + i) & (S_ - 1);   // position within sequence
#pragma unroll
      for (int jj = 0; jj < 4; ++jj) {
        float ang = (float)srow * invf[jj];
        float sn, cs;
        sincosf(ang, &sn, &cs);
        float x1 = acc[i][jj], x2 = acc[i][jj + 4];
        acc[i][jj]     = x1 * cs - x2 * sn;
        acc[i][jj + 4] = x2 * cs + x1 * sn;
      }
    }
  }

#pragma unroll
  for (int i = 0; i < 8; ++i) {
    float* Crow = C + (size_t)(m0 + ty * 8 + i) * N + n0;
    *(float4*)(Crow + tx * 4) =
        make_float4(acc[i][0], acc[i][1], acc[i][2], acc[i][3]);
    *(float4*)(Crow + 64 + tx * 4) =
        make_float4(acc[i][4], acc[i][5], acc[i][6], acc[i][7]);
  }
}

// ---------------------------------------------------------------------------
// fp32 causal flash attention. One block = 64 q rows of one (b,h).
// 256 threads as 16(ty) x 16(tx); scores 64x32 (4x2/thread, cols j*16+tx so
// K-reads are 16 consecutive granules); PV output 4 rows x 8 cols/thread
// (cols tx*4+jj and 64+tx*4+jj for float4 V reads). K and V time-share one
// LDS buffer. LDS total 59.4 KB -> 2 blocks/CU.
// ---------------------------------------------------------------------------
__global__ __launch_bounds__(256) void attn_kernel(
    const float* __restrict__ qkv, float* __restrict__ out) {
  const int qt = gridDim.x - 1 - blockIdx.x;   // heavy (long-loop) blocks first
  const int bh = blockIdx.y;
  const int b = bh >> 4, h = bh & (H_ - 1);
  const int tid = threadIdx.x;
  const int ty = tid >> 4, tx = tid & 15;

  __shared__ float Qs[QT][HD_ + 4];
  __shared__ float KVs[KT][HD_ + 4];
  __shared__ float Ps[QT][KT + 2];

  const float* qbase = qkv + ((size_t)b * S_ + (size_t)qt * QT) * NQKV_ + h * HD_;
#pragma unroll
  for (int it = 0; it < (QT * HD_) / (4 * 256); ++it) {
    int f = tid + it * 256;
    int r = f >> 5, c4 = f & 31;
    *(float4*)&Qs[r][c4 * 4] = *(const float4*)(qbase + (size_t)r * NQKV_ + c4 * 4);
  }

  float m_i[4], l_i[4], accO[4][8];
#pragma unroll
  for (int i = 0; i < 4; ++i) {
    m_i[i] = -INFINITY;
    l_i[i] = 0.f;
#pragma unroll
    for (int jj = 0; jj < 8; ++jj) accO[i][jj] = 0.f;
  }

  const int nkt = 2 * (qt + 1);                 // causal: only tiles <= diagonal
  const float scale = 0.08838834764831845f;     // 1/sqrt(128)

  for (int kt = 0; kt < nkt; ++kt) {
    __syncthreads();   // protect KVs (V of prev iter) and, on iter 0, Qs
    {
      const float* kb = qkv + ((size_t)b * S_ + (size_t)kt * KT) * NQKV_ +
                        H_ * HD_ + h * HD_;
#pragma unroll
      for (int it = 0; it < (KT * HD_) / (4 * 256); ++it) {
        int f = tid + it * 256;
        int r = f >> 5, c4 = f & 31;
        *(float4*)&KVs[r][c4 * 4] = *(const float4*)(kb + (size_t)r * NQKV_ + c4 * 4);
      }
    }
    __syncthreads();

    // scores: S[ty*4+i][j*16+tx] over d=0..127
    float sc0[4] = {0, 0, 0, 0}, sc1[4] = {0, 0, 0, 0};
#pragma unroll 8
    for (int d4 = 0; d4 < HD_ / 4; ++d4) {
      float4 k0v = *(const float4*)&KVs[tx][d4 * 4];
      float4 k1v = *(const float4*)&KVs[16 + tx][d4 * 4];
#pragma unroll
      for (int i = 0; i < 4; ++i) {
        float4 qv = *(const float4*)&Qs[ty * 4 + i][d4 * 4];
        sc0[i] += qv.x * k0v.x + qv.y * k0v.y + qv.z * k0v.z + qv.w * k0v.w;
        sc1[i] += qv.x * k1v.x + qv.y * k1v.y + qv.z * k1v.z + qv.w * k1v.w;
      }
    }

    // online softmax (per-row stats replicated across the 16 tx lanes)
    const int qrow0 = qt * QT + ty * 4;
    const int kc = kt * KT + tx;
    float alpha[4];
#pragma unroll
    for (int i = 0; i < 4; ++i) {
      int qr = qrow0 + i;
      float s0 = (kc <= qr) ? sc0[i] * scale : -INFINITY;
      float s1 = (kc + 16 <= qr) ? sc1[i] * scale : -INFINITY;
      float tmax = fmaxf(s0, s1);
#pragma unroll
      for (int off = 8; off > 0; off >>= 1)
        tmax = fmaxf(tmax, __shfl_xor(tmax, off, 16));
      float mn = fmaxf(m_i[i], tmax);
      float p0 = __expf(s0 - mn);                 // masked -> exp(-inf) = 0
      float p1 = __expf(s1 - mn);
      float al = __expf(m_i[i] - mn);             // first tile: exp(-inf) = 0
      float rs = p0 + p1;
#pragma unroll
      for (int off = 8; off > 0; off >>= 1) rs += __shfl_xor(rs, off, 16);
      l_i[i] = l_i[i] * al + rs;
      m_i[i] = mn;
      alpha[i] = al;
      Ps[ty * 4 + i][tx] = p0;
      Ps[ty * 4 + i][16 + tx] = p1;
    }

    __syncthreads();   // Ps written; K-reads done -> safe to overwrite with V
    {
      const float* vb = qkv + ((size_t)b * S_ + (size_t)kt * KT) * NQKV_ +
                        2 * H_ * HD_ + h * HD_;
#pragma unroll
      for (int it = 0; it < (KT * HD_) / (4 * 256); ++it) {
        int f = tid + it * 256;
        int r = f >> 5, c4 = f & 31;
        *(float4*)&KVs[r][c4 * 4] = *(const float4*)(vb + (size_t)r * NQKV_ + c4 * 4);
      }
    }
    __syncthreads();

#pragma unroll
    for (int i = 0; i < 4; ++i)
#pragma unroll
      for (int jj = 0; jj < 8; ++jj) accO[i][jj] *= alpha[i];

#pragma unroll 4
    for (int j = 0; j < KT; ++j) {
      float4 v0 = *(const float4*)&KVs[j][tx * 4];
      float4 v1 = *(const float4*)&KVs[j][64 + tx * 4];
#pragma unroll
      for (int i = 0; i < 4; ++i) {
        float p = Ps[ty * 4 + i][j];   // broadcast read, conflict-free
        accO[i][0] = fmaf(p, v0.x, accO[i][0]);
        accO[i][1] = fmaf(p, v0.y, accO[i][1]);
        accO[i][2] = fmaf(p, v0.z, accO[i][2]);
        accO[i][3] = fmaf(p, v0.w, accO[i][3]);
        accO[i][4] = fmaf(p, v1.x, accO[i][4]);
        accO[i][5] = fmaf(p, v1.y, accO[i][5]);
        accO[i][6] = fmaf(p, v1.z, accO[i][6]);
        accO[i][7] = fmaf(p, v1.w, accO[i][7]);
      }
    }
  }

  // epilogue: divide by l, write [b, s, h*HD + d] (ready for O-projection GEMM)
#pragma unroll
  for (int i = 0; i < 4; ++i) {
    float inv_l = 1.0f / l_i[i];
    float* orow = out + ((size_t)b * S_ + (size_t)qt * QT + ty * 4 + i) * (H_ * HD_) +
                  h * HD_;
    *(float4*)(orow + tx * 4) = make_float4(accO[i][0] * inv_l, accO[i][1] * inv_l,
                                            accO[i][2] * inv_l, accO[i][3] * inv_l);
    *(float4*)(orow + 64 + tx * 4) = make_float4(accO[i][4] * inv_l, accO[i][5] * inv_l,
                                                 accO[i][6] * inv_l, accO[i][7] * inv_l);
  }
}

// ---------------------------------------------------------------------------
extern "C" void kernel_launch(void* const* d_in, const int* in_sizes, int n_in,
                              void* d_out, int out_size, void* d_ws, size_t ws_size,
                              hipStream_t stream) {
  const float* x    = (const float*)d_in[0];   // [B,S,D]
  const float* Wqkv = (const float*)d_in[1];   // [D, 3*H*HD]
  const float* Wo   = (const float*)d_in[2];   // [H*HD, D]
  float* out = (float*)d_out;                  // [B,S,D]

  float* qkv  = (float*)d_ws;                        // [4096, 6144] = 100.7 MB
  float* attn = qkv + (size_t)M_ * NQKV_;            // [4096, 2048] =  33.6 MB

  // 1) QKV projection with fused RoPE epilogue on Q/K heads
  gemm_f32_kernel<true><<<dim3(NQKV_ / 128, M_ / 128), 256, 0, stream>>>(
      x, Wqkv, qkv, M_, NQKV_, D_);

  // 2) causal flash attention
  attn_kernel<<<dim3(S_ / QT, B_ * H_), 256, 0, stream>>>(qkv, attn);

  // 3) output projection
  gemm_f32_kernel<false><<<dim3(D_ / 128, M_ / 128), 256, 0, stream>>>(
      attn, Wo, out, M_, D_, H_ * HD_);
}

// Round 6
// 1779.310 us; speedup vs baseline: 1.9157x; 1.9157x over previous
//
#include <hip/hip_runtime.h>
#include <math.h>

// Round 6: byte-equivalent resubmit (5th broker failure; kernel never ran).
// bf16-MFMA projection GEMMs + fp32 flash attn + standalone RoPE.
// Workspace peak 125.8 MB (< 134.3 MB proven by round 2's run).

#define B_    2
#define S_    2048
#define D_    2048
#define H_    16
#define HD_   128
#define M_    (B_ * S_)          // 4096
#define NQKV_ (3 * H_ * HD_)     // 6144

#define QT 64
#define KT 32

typedef __bf16 bf16x8 __attribute__((ext_vector_type(8)));
typedef float  f32x4  __attribute__((ext_vector_type(4)));

__device__ __forceinline__ unsigned short f32_bf16(float f) {
  unsigned int u = __float_as_uint(f);
  u = (u + 0x7fffu + ((u >> 16) & 1u)) >> 16;   // round-to-nearest-even
  return (unsigned short)u;
}

__device__ __forceinline__ void gload_lds16(const void* g, void* lds) {
  __builtin_amdgcn_global_load_lds(
      (const __attribute__((address_space(1))) unsigned int*)g,
      (__attribute__((address_space(3))) unsigned int*)lds, 16, 0, 0);
}

// ---------------------------------------------------------------------------
// elementwise f32 -> bf16, float4 in / ushort4 out
// ---------------------------------------------------------------------------
__global__ __launch_bounds__(256) void cvt_bf16_kernel(
    const float* __restrict__ in, unsigned short* __restrict__ out, int n4) {
  int i = blockIdx.x * blockDim.x + threadIdx.x;
  if (i >= n4) return;
  float4 v = ((const float4*)in)[i];
  ((ushort4*)out)[i] =
      make_ushort4(f32_bf16(v.x), f32_bf16(v.y), f32_bf16(v.z), f32_bf16(v.w));
}

// ---------------------------------------------------------------------------
// transpose + convert a column slice: in [K][ldin] f32, cols [ncol0, ncol0+N)
// -> out [N][K] bf16. 32x32 LDS tile, +1 pad.
// ---------------------------------------------------------------------------
__global__ __launch_bounds__(1024) void cvt_t_kernel(
    const float* __restrict__ in, unsigned short* __restrict__ out,
    int K, int ldin, int ncol0) {
  __shared__ float t[32][33];
  const int n0 = blockIdx.x * 32, k0 = blockIdx.y * 32;
  const int tx = threadIdx.x & 31, ty = threadIdx.x >> 5;
  t[ty][tx] = in[(size_t)(k0 + ty) * ldin + ncol0 + n0 + tx];
  __syncthreads();
  out[(size_t)(n0 + ty) * K + k0 + tx] = f32_bf16(t[tx][ty]);
}

// ---------------------------------------------------------------------------
// standalone RoPE on fp32 qkv[4096][6144], q+k head-sections (0..31).
// block 256 = 4 sections x 64 pair-indices; grid (4096, 8).
// ---------------------------------------------------------------------------
__global__ __launch_bounds__(256) void rope_kernel(float* __restrict__ qkv) {
  const int row = blockIdx.x;
  const int sec = blockIdx.y * 4 + (threadIdx.x >> 6);    // 0..31 (q then k)
  const int d   = threadIdx.x & 63;
  const int pos = row & (S_ - 1);
  // inv_freq = 10000^(-d/64) = 2^(-d*log2(1e4)/64)
  float invf = exp2f(-(float)d * (13.287712379549449f / 64.0f));
  float ang = (float)pos * invf;
  float sn, cs;
  sincosf(ang, &sn, &cs);
  float* p = qkv + (size_t)row * NQKV_ + sec * HD_ + d;
  float x1 = p[0], x2 = p[64];
  p[0]  = x1 * cs - x2 * sn;
  p[64] = x2 * cs + x1 * sn;
}

// ---------------------------------------------------------------------------
// bf16 MFMA GEMM (m97 structure): C_f32[M][ldc] (cols n0..) =
//   A_bf16[M][K] @ Bt_bf16[N][K]^T.  128x128 tile, BK=32, 4 waves (2x2 of
//   64x64), mfma_f32_16x16x32_bf16, 4x4 frags/wave, global_load_lds w=16.
// ---------------------------------------------------------------------------
__global__ __launch_bounds__(256) void gemm_bt_bf16(
    const unsigned short* __restrict__ A, const unsigned short* __restrict__ Bt,
    float* __restrict__ C, int M, int N, int K, int ldc) {
  constexpr int BK = 32;
  __shared__ unsigned short As[128 * BK];   // [128 m][32 k] row-major
  __shared__ unsigned short Bs[128 * BK];   // [128 n][32 k] row-major
  const int tid = threadIdx.x;
  const int wid = tid >> 6, lane = tid & 63;
  const int wr = wid >> 1, wc = wid & 1;
  const int m0 = blockIdx.y * 128, n0 = blockIdx.x * 128;

  const char* Ab = (const char*)(A + (size_t)m0 * K);
  const char* Bb = (const char*)(Bt + (size_t)n0 * K);
  char* AsB = (char*)As;
  char* BsB = (char*)Bs;
  const size_t rowbytes = (size_t)K * 2;

  f32x4 acc[4][4];
#pragma unroll
  for (int i = 0; i < 4; ++i)
#pragma unroll
    for (int j = 0; j < 4; ++j) acc[i][j] = (f32x4){0.f, 0.f, 0.f, 0.f};

  const int r16 = lane & 15, kg = lane >> 4;

  for (int k0 = 0; k0 < K; k0 += BK) {
    // stage A,B tiles: 512 16B chunks each; wave w stages chunks w*128..+127
#pragma unroll
    for (int c = 0; c < 2; ++c) {
      int q = wid * 128 + c * 64 + lane;            // chunk 0..511
      size_t goff = (size_t)(q >> 2) * rowbytes + (size_t)k0 * 2 + (q & 3) * 16;
      int loff = wid * 2048 + c * 1024;             // wave-uniform LDS base
      gload_lds16(Ab + goff, AsB + loff);
      gload_lds16(Bb + goff, BsB + loff);
    }
    __syncthreads();

    bf16x8 af[4], bfr[4];
#pragma unroll
    for (int i = 0; i < 4; ++i)
      af[i] = *(const bf16x8*)(As + (wr * 64 + i * 16 + r16) * BK + kg * 8);
#pragma unroll
    for (int j = 0; j < 4; ++j)
      bfr[j] = *(const bf16x8*)(Bs + (wc * 64 + j * 16 + r16) * BK + kg * 8);
#pragma unroll
    for (int i = 0; i < 4; ++i)
#pragma unroll
      for (int j = 0; j < 4; ++j)
        acc[i][j] = __builtin_amdgcn_mfma_f32_16x16x32_bf16(af[i], bfr[j],
                                                            acc[i][j], 0, 0, 0);
    __syncthreads();
  }

  // C/D layout (m89-verified): col = lane&15, row = (lane>>4)*4 + reg
#pragma unroll
  for (int i = 0; i < 4; ++i) {
    int row = m0 + wr * 64 + i * 16 + (lane >> 4) * 4;
#pragma unroll
    for (int j = 0; j < 4; ++j) {
      float* cp = C + (size_t)row * ldc + n0 + wc * 64 + j * 16 + (lane & 15);
      cp[0]                = acc[i][j][0];
      cp[(size_t)ldc]      = acc[i][j][1];
      cp[(size_t)2 * ldc]  = acc[i][j][2];
      cp[(size_t)3 * ldc]  = acc[i][j][3];
    }
  }
}

// ---------------------------------------------------------------------------
// fp32 causal flash attention (verified round-2 kernel; epilogue -> bf16 out)
// ---------------------------------------------------------------------------
__global__ __launch_bounds__(256) void attn_kernel(
    const float* __restrict__ qkv, unsigned short* __restrict__ out) {
  const int qt = gridDim.x - 1 - blockIdx.x;
  const int bh = blockIdx.y;
  const int b = bh >> 4, h = bh & (H_ - 1);
  const int tid = threadIdx.x;
  const int ty = tid >> 4, tx = tid & 15;

  __shared__ float Qs[QT][HD_ + 4];
  __shared__ float KVs[KT][HD_ + 4];
  __shared__ float Ps[QT][KT + 2];

  const float* qbase = qkv + ((size_t)b * S_ + (size_t)qt * QT) * NQKV_ + h * HD_;
#pragma unroll
  for (int it = 0; it < (QT * HD_) / (4 * 256); ++it) {
    int f = tid + it * 256;
    int r = f >> 5, c4 = f & 31;
    *(float4*)&Qs[r][c4 * 4] = *(const float4*)(qbase + (size_t)r * NQKV_ + c4 * 4);
  }

  float m_i[4], l_i[4], accO[4][8];
#pragma unroll
  for (int i = 0; i < 4; ++i) {
    m_i[i] = -INFINITY;
    l_i[i] = 0.f;
#pragma unroll
    for (int jj = 0; jj < 8; ++jj) accO[i][jj] = 0.f;
  }

  const int nkt = 2 * (qt + 1);
  const float scale = 0.08838834764831845f;

  for (int kt = 0; kt < nkt; ++kt) {
    __syncthreads();
    {
      const float* kb = qkv + ((size_t)b * S_ + (size_t)kt * KT) * NQKV_ +
                        H_ * HD_ + h * HD_;
#pragma unroll
      for (int it = 0; it < (KT * HD_) / (4 * 256); ++it) {
        int f = tid + it * 256;
        int r = f >> 5, c4 = f & 31;
        *(float4*)&KVs[r][c4 * 4] = *(const float4*)(kb + (size_t)r * NQKV_ + c4 * 4);
      }
    }
    __syncthreads();

    float sc0[4] = {0, 0, 0, 0}, sc1[4] = {0, 0, 0, 0};
#pragma unroll 8
    for (int d4 = 0; d4 < HD_ / 4; ++d4) {
      float4 k0v = *(const float4*)&KVs[tx][d4 * 4];
      float4 k1v = *(const float4*)&KVs[16 + tx][d4 * 4];
#pragma unroll
      for (int i = 0; i < 4; ++i) {
        float4 qv = *(const float4*)&Qs[ty * 4 + i][d4 * 4];
        sc0[i] += qv.x * k0v.x + qv.y * k0v.y + qv.z * k0v.z + qv.w * k0v.w;
        sc1[i] += qv.x * k1v.x + qv.y * k1v.y + qv.z * k1v.z + qv.w * k1v.w;
      }
    }

    const int qrow0 = qt * QT + ty * 4;
    const int kc = kt * KT + tx;
    float alpha[4];
#pragma unroll
    for (int i = 0; i < 4; ++i) {
      int qr = qrow0 + i;
      float s0 = (kc <= qr) ? sc0[i] * scale : -INFINITY;
      float s1 = (kc + 16 <= qr) ? sc1[i] * scale : -INFINITY;
      float tmax = fmaxf(s0, s1);
#pragma unroll
      for (int off = 8; off > 0; off >>= 1)
        tmax = fmaxf(tmax, __shfl_xor(tmax, off, 16));
      float mn = fmaxf(m_i[i], tmax);
      float p0 = __expf(s0 - mn);
      float p1 = __expf(s1 - mn);
      float al = __expf(m_i[i] - mn);
      float rs = p0 + p1;
#pragma unroll
      for (int off = 8; off > 0; off >>= 1) rs += __shfl_xor(rs, off, 16);
      l_i[i] = l_i[i] * al + rs;
      m_i[i] = mn;
      alpha[i] = al;
      Ps[ty * 4 + i][tx] = p0;
      Ps[ty * 4 + i][16 + tx] = p1;
    }

    __syncthreads();
    {
      const float* vb = qkv + ((size_t)b * S_ + (size_t)kt * KT) * NQKV_ +
                        2 * H_ * HD_ + h * HD_;
#pragma unroll
      for (int it = 0; it < (KT * HD_) / (4 * 256); ++it) {
        int f = tid + it * 256;
        int r = f >> 5, c4 = f & 31;
        *(float4*)&KVs[r][c4 * 4] = *(const float4*)(vb + (size_t)r * NQKV_ + c4 * 4);
      }
    }
    __syncthreads();

#pragma unroll
    for (int i = 0; i < 4; ++i)
#pragma unroll
      for (int jj = 0; jj < 8; ++jj) accO[i][jj] *= alpha[i];

#pragma unroll 4
    for (int j = 0; j < KT; ++j) {
      float4 v0 = *(const float4*)&KVs[j][tx * 4];
      float4 v1 = *(const float4*)&KVs[j][64 + tx * 4];
#pragma unroll
      for (int i = 0; i < 4; ++i) {
        float p = Ps[ty * 4 + i][j];
        accO[i][0] = fmaf(p, v0.x, accO[i][0]);
        accO[i][1] = fmaf(p, v0.y, accO[i][1]);
        accO[i][2] = fmaf(p, v0.z, accO[i][2]);
        accO[i][3] = fmaf(p, v0.w, accO[i][3]);
        accO[i][4] = fmaf(p, v1.x, accO[i][4]);
        accO[i][5] = fmaf(p, v1.y, accO[i][5]);
        accO[i][6] = fmaf(p, v1.z, accO[i][6]);
        accO[i][7] = fmaf(p, v1.w, accO[i][7]);
      }
    }
  }

#pragma unroll
  for (int i = 0; i < 4; ++i) {
    float inv_l = 1.0f / l_i[i];
    unsigned short* orow = out +
        ((size_t)b * S_ + (size_t)qt * QT + ty * 4 + i) * (H_ * HD_) + h * HD_;
    *(ushort4*)(orow + tx * 4) =
        make_ushort4(f32_bf16(accO[i][0] * inv_l), f32_bf16(accO[i][1] * inv_l),
                     f32_bf16(accO[i][2] * inv_l), f32_bf16(accO[i][3] * inv_l));
    *(ushort4*)(orow + 64 + tx * 4) =
        make_ushort4(f32_bf16(accO[i][4] * inv_l), f32_bf16(accO[i][5] * inv_l),
                     f32_bf16(accO[i][6] * inv_l), f32_bf16(accO[i][7] * inv_l));
  }
}

// ---------------------------------------------------------------------------
extern "C" void kernel_launch(void* const* d_in, const int* in_sizes, int n_in,
                              void* d_out, int out_size, void* d_ws, size_t ws_size,
                              hipStream_t stream) {
  const float* x    = (const float*)d_in[0];   // [B,S,D]
  const float* Wqkv = (const float*)d_in[1];   // [D, 3*H*HD]  ([K][N])
  const float* Wo   = (const float*)d_in[2];   // [H*HD, D]    ([K][N])
  float* out = (float*)d_out;

  // workspace layout (bytes), peak 125.8 MB (proven-safe: round 2 used 134.3):
  //   [0, 100663296)            qkv  fp32 [4096][6144]
  //   [100663296, +16777216)    xb   bf16 [4096][2048] -> reused as attn bf16
  //   [117440512, +8388608)     wt   bf16 [2048][2048] (per-section weight^T)
  char* ws = (char*)d_ws;
  float* qkv            = (float*)ws;
  unsigned short* xb    = (unsigned short*)(ws + 100663296);
  unsigned short* attnb = xb;                                  // reuse
  unsigned short* wt    = (unsigned short*)(ws + 117440512);

  // 1) x -> bf16
  cvt_bf16_kernel<<<(M_ * D_ / 4 + 255) / 256, 256, 0, stream>>>(x, xb, M_ * D_ / 4);

  // 2) QKV projection, one 2048-col section at a time (q, k, v)
  for (int s = 0; s < 3; ++s) {
    cvt_t_kernel<<<dim3(D_ / 32, D_ / 32), 1024, 0, stream>>>(
        Wqkv, wt, D_, NQKV_, s * D_);
    gemm_bt_bf16<<<dim3(D_ / 128, M_ / 128), 256, 0, stream>>>(
        xb, wt, qkv + (size_t)s * D_, M_, D_, D_, NQKV_);
  }

  // 3) RoPE on q,k sections
  rope_kernel<<<dim3(M_, 8), 256, 0, stream>>>(qkv);

  // 4) causal flash attention (fp32 in, bf16 out; overwrites xb, dead now)
  attn_kernel<<<dim3(S_ / QT, B_ * H_), 256, 0, stream>>>(qkv, attnb);

  // 5) output projection
  cvt_t_kernel<<<dim3(D_ / 32, D_ / 32), 1024, 0, stream>>>(Wo, wt, H_ * HD_, D_, 0);
  gemm_bt_bf16<<<dim3(D_ / 128, M_ / 128), 256, 0, stream>>>(
      attnb, wt, out, M_, D_, H_ * HD_, D_);
}

// Round 10
// 625.324 us; speedup vs baseline: 5.4509x; 2.8454x over previous
//
#include <hip/hip_runtime.h>
#include <math.h>

// Round 10: byte-equivalent resubmit (8th broker failure; round-7 kernel has
// never run). bf16-MFMA flash attention (QT=64, KVT=64, 4 waves x 16 q-rows).
// Q/K via swizzled global_load_lds (chunk ^ (row&7)); V reg-staged transposed
// into padded Vt[128][72]; P per-wave LDS round-trip; S/softmax kept f32.
// qkv pipeline fully bf16 (GEMM bf16 out, RoPE bf16). WS peak 75.5 MB.

#define B_    2
#define S_    2048
#define D_    2048
#define H_    16
#define HD_   128
#define M_    (B_ * S_)          // 4096
#define NQKV_ (3 * H_ * HD_)     // 6144

typedef __bf16 bf16x8 __attribute__((ext_vector_type(8)));
typedef float  f32x4  __attribute__((ext_vector_type(4)));
typedef unsigned short u16x8 __attribute__((ext_vector_type(8)));

__device__ __forceinline__ unsigned short f32_bf16(float f) {
  unsigned int u = __float_as_uint(f);
  u = (u + 0x7fffu + ((u >> 16) & 1u)) >> 16;   // round-to-nearest-even
  return (unsigned short)u;
}
__device__ __forceinline__ float bf16_f32(unsigned short u) {
  return __uint_as_float(((unsigned int)u) << 16);
}

__device__ __forceinline__ void gload_lds16(const void* g, void* lds) {
  __builtin_amdgcn_global_load_lds(
      (const __attribute__((address_space(1))) unsigned int*)g,
      (__attribute__((address_space(3))) unsigned int*)lds, 16, 0, 0);
}

// ---------------------------------------------------------------------------
__global__ __launch_bounds__(256) void cvt_bf16_kernel(
    const float* __restrict__ in, unsigned short* __restrict__ out, int n4) {
  int i = blockIdx.x * blockDim.x + threadIdx.x;
  if (i >= n4) return;
  float4 v = ((const float4*)in)[i];
  ((ushort4*)out)[i] =
      make_ushort4(f32_bf16(v.x), f32_bf16(v.y), f32_bf16(v.z), f32_bf16(v.w));
}

// transpose+convert column slice: in [K][ldin] f32 -> out [N][K] bf16
__global__ __launch_bounds__(1024) void cvt_t_kernel(
    const float* __restrict__ in, unsigned short* __restrict__ out,
    int K, int ldin, int ncol0) {
  __shared__ float t[32][33];
  const int n0 = blockIdx.x * 32, k0 = blockIdx.y * 32;
  const int tx = threadIdx.x & 31, ty = threadIdx.x >> 5;
  t[ty][tx] = in[(size_t)(k0 + ty) * ldin + ncol0 + n0 + tx];
  __syncthreads();
  out[(size_t)(n0 + ty) * K + k0 + tx] = f32_bf16(t[tx][ty]);
}

// RoPE on bf16 qkv[4096][6144], q+k head-sections (0..31)
__global__ __launch_bounds__(256) void rope_bf16_kernel(
    unsigned short* __restrict__ qkv) {
  const int row = blockIdx.x;
  const int sec = blockIdx.y * 4 + (threadIdx.x >> 6);
  const int d   = threadIdx.x & 63;
  const int pos = row & (S_ - 1);
  float invf = exp2f(-(float)d * (13.287712379549449f / 64.0f));
  float ang = (float)pos * invf;
  float sn, cs;
  sincosf(ang, &sn, &cs);
  unsigned short* p = qkv + (size_t)row * NQKV_ + sec * HD_ + d;
  float x1 = bf16_f32(p[0]), x2 = bf16_f32(p[64]);
  p[0]  = f32_bf16(x1 * cs - x2 * sn);
  p[64] = f32_bf16(x2 * cs + x1 * sn);
}

// ---------------------------------------------------------------------------
// bf16 MFMA GEMM (m97 structure), templated output dtype.
// ---------------------------------------------------------------------------
template <bool OUT_BF16>
__global__ __launch_bounds__(256) void gemm_bt_bf16(
    const unsigned short* __restrict__ A, const unsigned short* __restrict__ Bt,
    void* __restrict__ Cv, int M, int N, int K, int ldc) {
  constexpr int BK = 32;
  __shared__ __align__(16) unsigned short As[128 * BK];
  __shared__ __align__(16) unsigned short Bs[128 * BK];
  const int tid = threadIdx.x;
  const int wid = tid >> 6, lane = tid & 63;
  const int wr = wid >> 1, wc = wid & 1;
  const int m0 = blockIdx.y * 128, n0 = blockIdx.x * 128;

  const char* Ab = (const char*)(A + (size_t)m0 * K);
  const char* Bb = (const char*)(Bt + (size_t)n0 * K);
  char* AsB = (char*)As;
  char* BsB = (char*)Bs;
  const size_t rowbytes = (size_t)K * 2;

  f32x4 acc[4][4];
#pragma unroll
  for (int i = 0; i < 4; ++i)
#pragma unroll
    for (int j = 0; j < 4; ++j) acc[i][j] = (f32x4){0.f, 0.f, 0.f, 0.f};

  const int r16 = lane & 15, kg = lane >> 4;

  for (int k0 = 0; k0 < K; k0 += BK) {
#pragma unroll
    for (int c = 0; c < 2; ++c) {
      int q = wid * 128 + c * 64 + lane;
      size_t goff = (size_t)(q >> 2) * rowbytes + (size_t)k0 * 2 + (q & 3) * 16;
      int loff = wid * 2048 + c * 1024;
      gload_lds16(Ab + goff, AsB + loff);
      gload_lds16(Bb + goff, BsB + loff);
    }
    __syncthreads();

    bf16x8 af[4], bfr[4];
#pragma unroll
    for (int i = 0; i < 4; ++i)
      af[i] = *(const bf16x8*)(As + (wr * 64 + i * 16 + r16) * BK + kg * 8);
#pragma unroll
    for (int j = 0; j < 4; ++j)
      bfr[j] = *(const bf16x8*)(Bs + (wc * 64 + j * 16 + r16) * BK + kg * 8);
#pragma unroll
    for (int i = 0; i < 4; ++i)
#pragma unroll
      for (int j = 0; j < 4; ++j)
        acc[i][j] = __builtin_amdgcn_mfma_f32_16x16x32_bf16(af[i], bfr[j],
                                                            acc[i][j], 0, 0, 0);
    __syncthreads();
  }

#pragma unroll
  for (int i = 0; i < 4; ++i) {
    int row = m0 + wr * 64 + i * 16 + (lane >> 4) * 4;
#pragma unroll
    for (int j = 0; j < 4; ++j) {
      int col = n0 + wc * 64 + j * 16 + (lane & 15);
      if constexpr (OUT_BF16) {
        unsigned short* cp = (unsigned short*)Cv + (size_t)row * ldc + col;
        cp[0]               = f32_bf16(acc[i][j][0]);
        cp[(size_t)ldc]     = f32_bf16(acc[i][j][1]);
        cp[(size_t)2 * ldc] = f32_bf16(acc[i][j][2]);
        cp[(size_t)3 * ldc] = f32_bf16(acc[i][j][3]);
      } else {
        float* cp = (float*)Cv + (size_t)row * ldc + col;
        cp[0]               = acc[i][j][0];
        cp[(size_t)ldc]     = acc[i][j][1];
        cp[(size_t)2 * ldc] = acc[i][j][2];
        cp[(size_t)3 * ldc] = acc[i][j][3];
      }
    }
  }
}

// ---------------------------------------------------------------------------
// bf16 MFMA causal flash attention.
// Block = 64 q-rows of one (b,h); 4 waves x 16 q-rows; KV tiles of 64.
// Qs/Ks: [64][128] bf16, 16B-chunk XOR-swizzled (chunk ^ (row&7)) so frag
// reads are evenly bank-spread; staged with swizzled-SOURCE global_load_lds.
// Vt: [128][72] padded transpose, reg-staged (lane=kv => 2-way writes).
// Ps: per-wave [16][72] P round-trip (same-wave DS ordering, no barrier).
// ---------------------------------------------------------------------------
__global__ __launch_bounds__(256) void attn_mfma_kernel(
    const unsigned short* __restrict__ qkv, unsigned short* __restrict__ out) {
  const int qt = (int)gridDim.x - 1 - (int)blockIdx.x;  // heavy blocks first
  const int bh = blockIdx.y;
  const int b = bh >> 4, h = bh & (H_ - 1);
  const int tid = threadIdx.x;
  const int w = tid >> 6, lane = tid & 63;
  const int r16 = lane & 15, kg = lane >> 4;

  __shared__ __align__(16) unsigned short Qs[64 * 128];
  __shared__ __align__(16) unsigned short Ks[64 * 128];
  __shared__ __align__(16) unsigned short Vt[128 * 72];
  __shared__ __align__(16) unsigned short Ps[4][16 * 72];

  const unsigned short* Qg = qkv + ((size_t)b * S_ + (size_t)qt * 64) * NQKV_ + h * HD_;
  const unsigned short* Kg = qkv + (size_t)b * S_ * NQKV_ + H_ * HD_ + h * HD_;
  const unsigned short* Vg = qkv + (size_t)b * S_ * NQKV_ + 2 * H_ * HD_ + h * HD_;

  // stage Q once: 1024 16B chunks, swizzled source
#pragma unroll
  for (int it = 0; it < 4; ++it) {
    int q = w * 256 + it * 64 + lane;
    int row = q >> 4, c = q & 15;
    int gc = c ^ (row & 7);
    gload_lds16(Qg + (size_t)row * NQKV_ + gc * 8, (char*)Qs + q * 16);
  }

  float m_i[4], l_i[4];
  f32x4 accO[8];
#pragma unroll
  for (int r = 0; r < 4; ++r) { m_i[r] = -INFINITY; l_i[r] = 0.f; }
#pragma unroll
  for (int jd = 0; jd < 8; ++jd) accO[jd] = (f32x4){0.f, 0.f, 0.f, 0.f};

  const float scale = 0.08838834764831845f;   // 1/sqrt(128)
  const int qg_row = qt * 64 + w * 16 + kg * 4;   // + r = global q row
  const int nkt = qt + 1;

  for (int kt = 0; kt < nkt; ++kt) {
    const int kv0 = kt * 64;
    __syncthreads();   // prev tile reads done (and Q ready on iter 0)

    // stage K tile (swizzled source, like Q)
#pragma unroll
    for (int it = 0; it < 4; ++it) {
      int q = w * 256 + it * 64 + lane;
      int row = q >> 4, c = q & 15;
      int gc = c ^ (row & 7);
      gload_lds16(Kg + (size_t)(kv0 + row) * NQKV_ + gc * 8, (char*)Ks + q * 16);
    }
    // stage V transposed: lane covers kv = lane, d-chunks w + it*4
    {
      const unsigned short* vr = Vg + (size_t)(kv0 + lane) * NQKV_;
#pragma unroll
      for (int it = 0; it < 4; ++it) {
        int dc = w + it * 4;                    // 0..15
        u16x8 v = *(const u16x8*)(vr + dc * 8);
#pragma unroll
        for (int j = 0; j < 8; ++j) Vt[(dc * 8 + j) * 72 + lane] = v[j];
      }
    }
    __syncthreads();

    // S = Q K^T for this wave's 16 q-rows x 64 kv
    f32x4 sc[4];
#pragma unroll
    for (int j = 0; j < 4; ++j) sc[j] = (f32x4){0.f, 0.f, 0.f, 0.f};
    {
      const int arow = w * 16 + r16;
      bf16x8 aq[4];
#pragma unroll
      for (int ks = 0; ks < 4; ++ks)
        aq[ks] = *(const bf16x8*)((const char*)Qs + arow * 256 +
                                  (((ks * 4 + kg) ^ (arow & 7)) * 16));
#pragma unroll
      for (int ks = 0; ks < 4; ++ks) {
#pragma unroll
        for (int j = 0; j < 4; ++j) {
          const int brow = j * 16 + r16;
          bf16x8 bk = *(const bf16x8*)((const char*)Ks + brow * 256 +
                                       (((ks * 4 + kg) ^ (brow & 7)) * 16));
          sc[j] = __builtin_amdgcn_mfma_f32_16x16x32_bf16(aq[ks], bk, sc[j], 0, 0, 0);
        }
      }
    }

    // online softmax (rows kg*4+r, stats in the 16-lane subgroup of kg)
    const bool diag = (kt == qt);
    float alpha[4];
#pragma unroll
    for (int r = 0; r < 4; ++r) {
      float sv[4];
#pragma unroll
      for (int j = 0; j < 4; ++j) {
        sv[j] = sc[j][r] * scale;
        if (diag && (kv0 + j * 16 + r16 > qg_row + r)) sv[j] = -INFINITY;
      }
      float tmax = fmaxf(fmaxf(sv[0], sv[1]), fmaxf(sv[2], sv[3]));
#pragma unroll
      for (int off = 8; off > 0; off >>= 1)
        tmax = fmaxf(tmax, __shfl_xor(tmax, off, 16));
      float mn = fmaxf(m_i[r], tmax);
      alpha[r] = __expf(m_i[r] - mn);
      m_i[r] = mn;
      float rs = 0.f;
#pragma unroll
      for (int j = 0; j < 4; ++j) {
        float p = __expf(sv[j] - mn);
        rs += p;
        Ps[w][(kg * 4 + r) * 72 + j * 16 + r16] = f32_bf16(p);
      }
#pragma unroll
      for (int off = 8; off > 0; off >>= 1) rs += __shfl_xor(rs, off, 16);
      l_i[r] = l_i[r] * alpha[r] + rs;
    }

    // rescale accumulator
#pragma unroll
    for (int jd = 0; jd < 8; ++jd)
#pragma unroll
      for (int r = 0; r < 4; ++r) accO[jd][r] *= alpha[r];

    // PV: O[16q][128d] += P[16q][64kv] * V[64kv][128d]
#pragma unroll
    for (int ks2 = 0; ks2 < 2; ++ks2) {
      bf16x8 pf = *(const bf16x8*)((const char*)&Ps[w][0] + r16 * 144 +
                                   ks2 * 64 + kg * 16);
#pragma unroll
      for (int jd = 0; jd < 8; ++jd) {
        bf16x8 vf = *(const bf16x8*)((const char*)Vt + (jd * 16 + r16) * 144 +
                                     ks2 * 64 + kg * 16);
        accO[jd] = __builtin_amdgcn_mfma_f32_16x16x32_bf16(pf, vf, accO[jd], 0, 0, 0);
      }
    }
  }

  // epilogue: /l, bf16, write [b,s,h*128+d]
  unsigned short* ob = out + ((size_t)b * S_ + (size_t)qt * 64 + w * 16) * (H_ * HD_) +
                       h * HD_;
#pragma unroll
  for (int r = 0; r < 4; ++r) {
    float inv_l = 1.0f / l_i[r];
    unsigned short* orow = ob + (size_t)(kg * 4 + r) * (H_ * HD_);
#pragma unroll
    for (int jd = 0; jd < 8; ++jd)
      orow[jd * 16 + r16] = f32_bf16(accO[jd][r] * inv_l);
  }
}

// ---------------------------------------------------------------------------
extern "C" void kernel_launch(void* const* d_in, const int* in_sizes, int n_in,
                              void* d_out, int out_size, void* d_ws, size_t ws_size,
                              hipStream_t stream) {
  const float* x    = (const float*)d_in[0];   // [B,S,D]
  const float* Wqkv = (const float*)d_in[1];   // [D, 3*H*HD]
  const float* Wo   = (const float*)d_in[2];   // [H*HD, D]
  float* out = (float*)d_out;

  // workspace (bytes), peak 75.5 MB:
  //   [0, 50331648)           qkvb bf16 [4096][6144]
  //   [50331648, +16777216)   xb   bf16 [4096][2048] -> reused as attnb
  //   [67108864, +8388608)    wt   bf16 [2048][2048]
  char* ws = (char*)d_ws;
  unsigned short* qkvb  = (unsigned short*)ws;
  unsigned short* xb    = (unsigned short*)(ws + 50331648);
  unsigned short* attnb = xb;
  unsigned short* wt    = (unsigned short*)(ws + 67108864);

  // 1) x -> bf16
  cvt_bf16_kernel<<<(M_ * D_ / 4 + 255) / 256, 256, 0, stream>>>(x, xb, M_ * D_ / 4);

  // 2) QKV projection (bf16 out), one 2048-col section at a time
  for (int s = 0; s < 3; ++s) {
    cvt_t_kernel<<<dim3(D_ / 32, D_ / 32), 1024, 0, stream>>>(
        Wqkv, wt, D_, NQKV_, s * D_);
    gemm_bt_bf16<true><<<dim3(D_ / 128, M_ / 128), 256, 0, stream>>>(
        xb, wt, qkvb + (size_t)s * D_, M_, D_, D_, NQKV_);
  }

  // 3) RoPE (bf16 in-place)
  rope_bf16_kernel<<<dim3(M_, 8), 256, 0, stream>>>(qkvb);

  // 4) bf16 MFMA causal flash attention
  attn_mfma_kernel<<<dim3(S_ / 64, B_ * H_), 256, 0, stream>>>(qkvb, attnb);

  // 5) output projection (f32 out)
  cvt_t_kernel<<<dim3(D_ / 32, D_ / 32), 1024, 0, stream>>>(Wo, wt, H_ * HD_, D_, 0);
  gemm_bt_bf16<false><<<dim3(D_ / 128, M_ / 128), 256, 0, stream>>>(
      attnb, wt, out, M_, D_, H_ * HD_, D_);
}

// Round 11
// 506.791 us; speedup vs baseline: 6.7258x; 1.2339x over previous
//
#include <hip/hip_runtime.h>
#include <math.h>

// Round 11: attention restructure — QT=128 (8 waves x 16 q-rows, 512 thr),
// Q in registers (no Qs LDS), K/V staged once per 128 q-rows (half traffic).
// LDS 52KB, __launch_bounds__(512,4) -> 2 blocks/CU = 16 waves/CU.
// QKV projection merged into one N=6144 GEMM (ws peak 92.3MB < 134.3 proven).

#define B_    2
#define S_    2048
#define D_    2048
#define H_    16
#define HD_   128
#define M_    (B_ * S_)          // 4096
#define NQKV_ (3 * H_ * HD_)     // 6144

typedef __bf16 bf16x8 __attribute__((ext_vector_type(8)));
typedef float  f32x4  __attribute__((ext_vector_type(4)));
typedef unsigned short u16x8 __attribute__((ext_vector_type(8)));

__device__ __forceinline__ unsigned short f32_bf16(float f) {
  unsigned int u = __float_as_uint(f);
  u = (u + 0x7fffu + ((u >> 16) & 1u)) >> 16;   // round-to-nearest-even
  return (unsigned short)u;
}
__device__ __forceinline__ float bf16_f32(unsigned short u) {
  return __uint_as_float(((unsigned int)u) << 16);
}

__device__ __forceinline__ void gload_lds16(const void* g, void* lds) {
  __builtin_amdgcn_global_load_lds(
      (const __attribute__((address_space(1))) unsigned int*)g,
      (__attribute__((address_space(3))) unsigned int*)lds, 16, 0, 0);
}

// ---------------------------------------------------------------------------
__global__ __launch_bounds__(256) void cvt_bf16_kernel(
    const float* __restrict__ in, unsigned short* __restrict__ out, int n4) {
  int i = blockIdx.x * blockDim.x + threadIdx.x;
  if (i >= n4) return;
  float4 v = ((const float4*)in)[i];
  ((ushort4*)out)[i] =
      make_ushort4(f32_bf16(v.x), f32_bf16(v.y), f32_bf16(v.z), f32_bf16(v.w));
}

// transpose+convert column slice: in [K][ldin] f32 -> out [N][K] bf16
__global__ __launch_bounds__(1024) void cvt_t_kernel(
    const float* __restrict__ in, unsigned short* __restrict__ out,
    int K, int ldin, int ncol0) {
  __shared__ float t[32][33];
  const int n0 = blockIdx.x * 32, k0 = blockIdx.y * 32;
  const int tx = threadIdx.x & 31, ty = threadIdx.x >> 5;
  t[ty][tx] = in[(size_t)(k0 + ty) * ldin + ncol0 + n0 + tx];
  __syncthreads();
  out[(size_t)(n0 + ty) * K + k0 + tx] = f32_bf16(t[tx][ty]);
}

// RoPE on bf16 qkv[4096][6144], q+k head-sections (0..31)
__global__ __launch_bounds__(256) void rope_bf16_kernel(
    unsigned short* __restrict__ qkv) {
  const int row = blockIdx.x;
  const int sec = blockIdx.y * 4 + (threadIdx.x >> 6);
  const int d   = threadIdx.x & 63;
  const int pos = row & (S_ - 1);
  float invf = exp2f(-(float)d * (13.287712379549449f / 64.0f));
  float ang = (float)pos * invf;
  float sn, cs;
  sincosf(ang, &sn, &cs);
  unsigned short* p = qkv + (size_t)row * NQKV_ + sec * HD_ + d;
  float x1 = bf16_f32(p[0]), x2 = bf16_f32(p[64]);
  p[0]  = f32_bf16(x1 * cs - x2 * sn);
  p[64] = f32_bf16(x2 * cs + x1 * sn);
}

// ---------------------------------------------------------------------------
// bf16 MFMA GEMM (m97 structure), templated output dtype.
// ---------------------------------------------------------------------------
template <bool OUT_BF16>
__global__ __launch_bounds__(256) void gemm_bt_bf16(
    const unsigned short* __restrict__ A, const unsigned short* __restrict__ Bt,
    void* __restrict__ Cv, int M, int N, int K, int ldc) {
  constexpr int BK = 32;
  __shared__ __align__(16) unsigned short As[128 * BK];
  __shared__ __align__(16) unsigned short Bs[128 * BK];
  const int tid = threadIdx.x;
  const int wid = tid >> 6, lane = tid & 63;
  const int wr = wid >> 1, wc = wid & 1;
  const int m0 = blockIdx.y * 128, n0 = blockIdx.x * 128;

  const char* Ab = (const char*)(A + (size_t)m0 * K);
  const char* Bb = (const char*)(Bt + (size_t)n0 * K);
  char* AsB = (char*)As;
  char* BsB = (char*)Bs;
  const size_t rowbytes = (size_t)K * 2;

  f32x4 acc[4][4];
#pragma unroll
  for (int i = 0; i < 4; ++i)
#pragma unroll
    for (int j = 0; j < 4; ++j) acc[i][j] = (f32x4){0.f, 0.f, 0.f, 0.f};

  const int r16 = lane & 15, kg = lane >> 4;

  for (int k0 = 0; k0 < K; k0 += BK) {
#pragma unroll
    for (int c = 0; c < 2; ++c) {
      int q = wid * 128 + c * 64 + lane;
      size_t goff = (size_t)(q >> 2) * rowbytes + (size_t)k0 * 2 + (q & 3) * 16;
      int loff = wid * 2048 + c * 1024;
      gload_lds16(Ab + goff, AsB + loff);
      gload_lds16(Bb + goff, BsB + loff);
    }
    __syncthreads();

    bf16x8 af[4], bfr[4];
#pragma unroll
    for (int i = 0; i < 4; ++i)
      af[i] = *(const bf16x8*)(As + (wr * 64 + i * 16 + r16) * BK + kg * 8);
#pragma unroll
    for (int j = 0; j < 4; ++j)
      bfr[j] = *(const bf16x8*)(Bs + (wc * 64 + j * 16 + r16) * BK + kg * 8);
#pragma unroll
    for (int i = 0; i < 4; ++i)
#pragma unroll
      for (int j = 0; j < 4; ++j)
        acc[i][j] = __builtin_amdgcn_mfma_f32_16x16x32_bf16(af[i], bfr[j],
                                                            acc[i][j], 0, 0, 0);
    __syncthreads();
  }

#pragma unroll
  for (int i = 0; i < 4; ++i) {
    int row = m0 + wr * 64 + i * 16 + (lane >> 4) * 4;
#pragma unroll
    for (int j = 0; j < 4; ++j) {
      int col = n0 + wc * 64 + j * 16 + (lane & 15);
      if constexpr (OUT_BF16) {
        unsigned short* cp = (unsigned short*)Cv + (size_t)row * ldc + col;
        cp[0]               = f32_bf16(acc[i][j][0]);
        cp[(size_t)ldc]     = f32_bf16(acc[i][j][1]);
        cp[(size_t)2 * ldc] = f32_bf16(acc[i][j][2]);
        cp[(size_t)3 * ldc] = f32_bf16(acc[i][j][3]);
      } else {
        float* cp = (float*)Cv + (size_t)row * ldc + col;
        cp[0]               = acc[i][j][0];
        cp[(size_t)ldc]     = acc[i][j][1];
        cp[(size_t)2 * ldc] = acc[i][j][2];
        cp[(size_t)3 * ldc] = acc[i][j][3];
      }
    }
  }
}

// ---------------------------------------------------------------------------
// bf16 MFMA causal flash attention, QT=128.
// Block = 128 q-rows of one (b,h); 8 waves x 16 q-rows; KV tiles of 64.
// Q: in registers (4x bf16x8/lane, loaded once). Ks: [64][128] bf16,
// 16B-chunk XOR-swizzled source (chunk ^ (row&7)). Vt: [128][72] padded
// transpose, reg-staged. Ps: per-wave [16][72] round-trip. LDS 52KB.
// ---------------------------------------------------------------------------
__global__ __launch_bounds__(512, 4) void attn_mfma_kernel(
    const unsigned short* __restrict__ qkv, unsigned short* __restrict__ out) {
  const int qt = (int)gridDim.x - 1 - (int)blockIdx.x;  // heavy blocks first
  const int bh = blockIdx.y;
  const int b = bh >> 4, h = bh & (H_ - 1);
  const int tid = threadIdx.x;
  const int w = tid >> 6, lane = tid & 63;
  const int r16 = lane & 15, kg = lane >> 4;

  __shared__ __align__(16) unsigned short Ks[64 * 128];
  __shared__ __align__(16) unsigned short Vt[128 * 72];
  __shared__ __align__(16) unsigned short Ps[8][16 * 72];

  const unsigned short* Kg = qkv + (size_t)b * S_ * NQKV_ + H_ * HD_ + h * HD_;
  const unsigned short* Vg = qkv + (size_t)b * S_ * NQKV_ + 2 * H_ * HD_ + h * HD_;

  // Q fragments straight to registers: row qt*128 + w*16 + r16, k-slices
  // ks*32 + kg*8 (A-frag mapping of mfma_f32_16x16x32_bf16).
  const unsigned short* Qg =
      qkv + ((size_t)b * S_ + (size_t)qt * 128 + w * 16 + r16) * NQKV_ + h * HD_;
  bf16x8 aq[4];
#pragma unroll
  for (int ks = 0; ks < 4; ++ks)
    aq[ks] = *(const bf16x8*)(Qg + ks * 32 + kg * 8);

  float m_i[4], l_i[4];
  f32x4 accO[8];
#pragma unroll
  for (int r = 0; r < 4; ++r) { m_i[r] = -INFINITY; l_i[r] = 0.f; }
#pragma unroll
  for (int jd = 0; jd < 8; ++jd) accO[jd] = (f32x4){0.f, 0.f, 0.f, 0.f};

  const float scale = 0.08838834764831845f;   // 1/sqrt(128)
  const int qg_row = qt * 128 + w * 16 + kg * 4;   // + r = global q row
  const int wave_qmin = qt * 128 + w * 16;
  const int nkt = 2 * (qt + 1);

  for (int kt = 0; kt < nkt; ++kt) {
    const int kv0 = kt * 64;
    __syncthreads();   // prev tile LDS reads done

    // stage K tile: 1024 16B chunks, 512 threads x 2, swizzled source
#pragma unroll
    for (int it = 0; it < 2; ++it) {
      int q = (w * 2 + it) * 64 + lane;             // chunk 0..1023
      int row = q >> 4, c = q & 15;
      int gc = c ^ (row & 7);
      gload_lds16(Kg + (size_t)(kv0 + row) * NQKV_ + gc * 8, (char*)Ks + q * 16);
    }
    // stage V transposed: lane covers kv = lane, d-chunks w + it*8
    {
      const unsigned short* vr = Vg + (size_t)(kv0 + lane) * NQKV_;
#pragma unroll
      for (int it = 0; it < 2; ++it) {
        int dc = w + it * 8;                        // 0..15
        u16x8 v = *(const u16x8*)(vr + dc * 8);
#pragma unroll
        for (int j = 0; j < 8; ++j) Vt[(dc * 8 + j) * 72 + lane] = v[j];
      }
    }
    __syncthreads();

    // S = Q K^T for this wave's 16 q-rows x 64 kv
    f32x4 sc[4];
#pragma unroll
    for (int j = 0; j < 4; ++j) sc[j] = (f32x4){0.f, 0.f, 0.f, 0.f};
#pragma unroll
    for (int ks = 0; ks < 4; ++ks) {
#pragma unroll
      for (int j = 0; j < 4; ++j) {
        const int brow = j * 16 + r16;
        bf16x8 bk = *(const bf16x8*)((const char*)Ks + brow * 256 +
                                     (((ks * 4 + kg) ^ (brow & 7)) * 16));
        sc[j] = __builtin_amdgcn_mfma_f32_16x16x32_bf16(aq[ks], bk, sc[j], 0, 0, 0);
      }
    }

    // online softmax (rows kg*4+r, stats in the 16-lane subgroup of kg)
    const bool diag = (kv0 + 63 > wave_qmin);   // any element maskable?
    float alpha[4];
#pragma unroll
    for (int r = 0; r < 4; ++r) {
      float sv[4];
#pragma unroll
      for (int j = 0; j < 4; ++j) {
        sv[j] = sc[j][r] * scale;
        if (diag && (kv0 + j * 16 + r16 > qg_row + r)) sv[j] = -INFINITY;
      }
      float tmax = fmaxf(fmaxf(sv[0], sv[1]), fmaxf(sv[2], sv[3]));
#pragma unroll
      for (int off = 8; off > 0; off >>= 1)
        tmax = fmaxf(tmax, __shfl_xor(tmax, off, 16));
      float mn = fmaxf(m_i[r], tmax);
      alpha[r] = __expf(m_i[r] - mn);
      m_i[r] = mn;
      float rs = 0.f;
#pragma unroll
      for (int j = 0; j < 4; ++j) {
        float p = __expf(sv[j] - mn);
        rs += p;
        Ps[w][(kg * 4 + r) * 72 + j * 16 + r16] = f32_bf16(p);
      }
#pragma unroll
      for (int off = 8; off > 0; off >>= 1) rs += __shfl_xor(rs, off, 16);
      l_i[r] = l_i[r] * alpha[r] + rs;
    }

    // rescale accumulator
#pragma unroll
    for (int jd = 0; jd < 8; ++jd)
#pragma unroll
      for (int r = 0; r < 4; ++r) accO[jd][r] *= alpha[r];

    // PV: O[16q][128d] += P[16q][64kv] * V[64kv][128d]
#pragma unroll
    for (int ks2 = 0; ks2 < 2; ++ks2) {
      bf16x8 pf = *(const bf16x8*)((const char*)&Ps[w][0] + r16 * 144 +
                                   ks2 * 64 + kg * 16);
#pragma unroll
      for (int jd = 0; jd < 8; ++jd) {
        bf16x8 vf = *(const bf16x8*)((const char*)Vt + (jd * 16 + r16) * 144 +
                                     ks2 * 64 + kg * 16);
        accO[jd] = __builtin_amdgcn_mfma_f32_16x16x32_bf16(pf, vf, accO[jd], 0, 0, 0);
      }
    }
  }

  // epilogue: /l, bf16, write [b,s,h*128+d]
  unsigned short* ob = out +
      ((size_t)b * S_ + (size_t)qt * 128 + w * 16) * (H_ * HD_) + h * HD_;
#pragma unroll
  for (int r = 0; r < 4; ++r) {
    float inv_l = 1.0f / l_i[r];
    unsigned short* orow = ob + (size_t)(kg * 4 + r) * (H_ * HD_);
#pragma unroll
    for (int jd = 0; jd < 8; ++jd)
      orow[jd * 16 + r16] = f32_bf16(accO[jd][r] * inv_l);
  }
}

// ---------------------------------------------------------------------------
extern "C" void kernel_launch(void* const* d_in, const int* in_sizes, int n_in,
                              void* d_out, int out_size, void* d_ws, size_t ws_size,
                              hipStream_t stream) {
  const float* x    = (const float*)d_in[0];   // [B,S,D]
  const float* Wqkv = (const float*)d_in[1];   // [D, 3*H*HD]
  const float* Wo   = (const float*)d_in[2];   // [H*HD, D]
  float* out = (float*)d_out;

  // workspace (bytes), peak 92.3 MB (< 134.3 proven):
  //   [0, 50331648)           qkvb bf16 [4096][6144]
  //   [50331648, +16777216)   xb   bf16 [4096][2048] -> reused as attnb
  //   [67108864, +25165824)   wt   bf16 [6144][2048] -> reused for Wo_t
  char* ws = (char*)d_ws;
  unsigned short* qkvb  = (unsigned short*)ws;
  unsigned short* xb    = (unsigned short*)(ws + 50331648);
  unsigned short* attnb = xb;
  unsigned short* wt    = (unsigned short*)(ws + 67108864);

  // 1) x -> bf16
  cvt_bf16_kernel<<<(M_ * D_ / 4 + 255) / 256, 256, 0, stream>>>(x, xb, M_ * D_ / 4);

  // 2) QKV projection, single merged GEMM over N=6144
  cvt_t_kernel<<<dim3(NQKV_ / 32, D_ / 32), 1024, 0, stream>>>(
      Wqkv, wt, D_, NQKV_, 0);
  gemm_bt_bf16<true><<<dim3(NQKV_ / 128, M_ / 128), 256, 0, stream>>>(
      xb, wt, qkvb, M_, NQKV_, D_, NQKV_);

  // 3) RoPE (bf16 in-place)
  rope_bf16_kernel<<<dim3(M_, 8), 256, 0, stream>>>(qkvb);

  // 4) bf16 MFMA causal flash attention (QT=128, 512 threads)
  attn_mfma_kernel<<<dim3(S_ / 128, B_ * H_), 512, 0, stream>>>(qkvb, attnb);

  // 5) output projection (f32 out)
  cvt_t_kernel<<<dim3(D_ / 32, D_ / 32), 1024, 0, stream>>>(Wo, wt, H_ * HD_, D_, 0);
  gemm_bt_bf16<false><<<dim3(D_ / 128, M_ / 128), 256, 0, stream>>>(
      attnb, wt, out, M_, D_, H_ * HD_, D_);
}